// Round 10
// baseline (52.392 us; speedup 1.0000x reference)
//
#include <hip/hip_runtime.h>

// ---------- types ----------
typedef __attribute__((ext_vector_type(8))) short bf16x8;
typedef __attribute__((ext_vector_type(4))) float f32x4;

__device__ __forceinline__ short f2bf(float f) {
  unsigned u = __builtin_bit_cast(unsigned, f);
  u += 0x7fffu + ((u >> 16) & 1u);   // round-to-nearest-even
  return (short)(u >> 16);
}

// ---------- layout ----------
// IN=4096, OUT=4096, RANK=1024, GROUP=128, PACK=8
// GEMM: out[n*4096+m] = sum_r W_V(m,r)*S(r) * W_U(r,n)
// A,B stored FRAGMENT-MAJOR: element addr = ((panel*16+kt)*32 + blk)*512 + lane*8 + e
//   A blk = h*16 + i*2 + kk (h = 128-row half, i = 16-row frag, kk = 32-k half)
//   B blk = q*8 + j*2 + kk  (q = 64-col quarter, j = 16-col frag)
// Each 1024-B block is one MFMA fragment in lane order: GLL copies contiguously,
// ds_read_b128 is stride-1 across lanes (conflict-free); half-tiles are 16 KB
// contiguous in global.

// ---------- stage 1: fused dequant (V -> A, U -> B) ----------
__global__ __launch_bounds__(256) void dequant_fused(
    const int* __restrict__ qw_V, const int* __restrict__ qz_V,
    const float* __restrict__ sc_V, const float* __restrict__ S,
    short* __restrict__ A,
    const int* __restrict__ qw_U, const int* __restrict__ qz_U,
    const float* __restrict__ sc_U, short* __restrict__ B) {
  const int bid = blockIdx.x;
  if (bid < 2048) {
    const int t    = bid * 256 + threadIdx.x;
    const int tile = t >> 11;
    const int blk  = (t >> 6) & 31;
    const int lane = t & 63;
    const int panel = tile >> 4, kt = tile & 15;
    const int m  = (panel << 8) + (((blk >> 4) & 1) << 7) + (((blk >> 1) & 7) << 4) + (lane & 15);
    const int r0 = (kt << 6) + ((blk & 1) << 5) + ((lane >> 4) << 3);
    const int g  = m >> 7;
    const int sh = (m & 7) << 2;
    const int zw = qz_V[(g << 7) + (r0 >> 3)];
    const int*   wq  = qw_V + (m >> 3) * 1024 + r0;
    const float* scp = sc_V + (g << 10) + r0;
    const float* sp  = S + r0;
    bf16x8 res;
#pragma unroll
    for (int e = 0; e < 8; ++e) {
      int q = (wq[e] >> sh) & 15;
      int z = ((zw >> (e << 2)) & 15) + 1;
      res[e] = f2bf((float)(q - z) * scp[e] * sp[e]);
    }
    *(bf16x8*)(A + ((size_t)t << 3)) = res;
  } else {
    const int t    = (bid - 2048) * 256 + threadIdx.x;
    const int tile = t >> 11;
    const int blk  = (t >> 6) & 31;
    const int lane = t & 63;
    const int panel = tile >> 4, kt = tile & 15;
    const int n  = (panel << 8) + (((blk >> 3) & 3) << 6) + (((blk >> 1) & 3) << 4) + (lane & 15);
    const int r0 = (kt << 6) + ((blk & 1) << 5) + ((lane >> 4) << 3);
    const int w  = qw_U[(r0 >> 3) * 4096 + n];
    const int g  = r0 >> 7;
    const int zw = qz_U[(g << 9) + (n >> 3)];
    const int z  = ((zw >> ((n & 7) << 2)) & 15) + 1;
    const float s = sc_U[(g << 12) + n];
    bf16x8 res;
#pragma unroll
    for (int e = 0; e < 8; ++e) {
      int q = (w >> (e << 2)) & 15;
      res[e] = f2bf((float)(q - z) * s);
    }
    *(bf16x8*)(B + ((size_t)t << 3)) = res;
  }
}

// ---------- stage 2: m201-style 8-phase, 2 K-tiles/iter ----------
// LDS: A slots 0..3 (16 KB each) at slot*16384; B slots at 65536 + slot*16384.
// Tile t uses A/B slots {(t&1)*2 + half}. Per phase: quadrant ds_reads; ONE
// half-tile stage (2 GLL); barrier; lgkm(0); 16 MFMA; barrier.
// Stage rolling schedule (iter it, tiles t0=2it, t0+1):
//   P0:A(t0+1)h0 P1:A(t0+1)h1 P2:B(t0+2)h0 P3:B(t0+2)h1 [vmcnt(4)]
//   P4:A(t0+2)h0 P5:A(t0+2)h1 P6:B(t0+3)h0 P7:B(t0+3)h1 [vmcnt(4)]
// Release ledger: B slots of tile t free after t's 2nd-phase barrier (bh0/bh1
// reg-held); A slots free after t's 3rd-phase barrier. Every stage target is
// released at least 1 barrier before its stage issues. vmcnt(4) retires
// exactly the next-needed tile's 8 GLLs. Last iter: no stages, vmcnt(0) at P3.
#define GLL(g, l)                                                              \
  __builtin_amdgcn_global_load_lds(                                            \
      (const __attribute__((address_space(1))) void*)(g),                      \
      (__attribute__((address_space(3))) void*)(l), 16, 0, 0)

__global__ __launch_bounds__(512, 2) void gemm256(const short* __restrict__ A,
                                                  const short* __restrict__ B,
                                                  float* __restrict__ out) {
  __shared__ __align__(16) char lds[131072];
  const int tid  = threadIdx.x;          // 0..511
  const int lane = tid & 63;
  const int wid  = tid >> 6;             // 0..7
  const int wm   = wid >> 2;             // 0..1
  const int wn   = wid & 3;              // 0..3
  const int bid = ((blockIdx.x & 7) << 5) | (blockIdx.x >> 3);  // T1 bijective
  const int mp = bid >> 4;
  const int np = bid & 15;

  // staging pointers: per-lane global (tid*16 B), wave-uniform LDS offset
  const short* gAp = A + (size_t)mp * 262144 + tid * 8;
  const short* gBp = B + (size_t)np * 262144 + tid * 8;
  const int wofs = wid << 10;

#define STGA_H(tile, half) do {                                                \
    const short* s_ = gAp + (tile) * 16384 + (half) * 8192;                    \
    char* d_ = lds + ((((tile) & 1) * 2 + (half)) << 14) + wofs;               \
    GLL(s_, d_);                                                               \
    GLL(s_ + 4096, d_ + 8192);                                                 \
  } while (0)
#define STGB_H(tile, half) do {                                                \
    const short* s_ = gBp + (tile) * 16384 + (half) * 8192;                    \
    char* d_ = lds + 65536 + ((((tile) & 1) * 2 + (half)) << 14) + wofs;       \
    GLL(s_, d_);                                                               \
    GLL(s_ + 4096, d_ + 8192);                                                 \
  } while (0)

  // per-wave read bases (byte offsets into lds), indexed by tile parity.
  // A frag block (h,i,kk): slot (par*2+h), block (i*2+kk) within 16 KB slot.
  // B frag block (q,j,kk): slot (par*2 + (wn>>1)), half (wn&1)*8KB.
  const char* aB[2];
  const char* bB[2];
  aB[0] = lds + (wm << 14) + (lane << 4);
  aB[1] = lds + ((2 + wm) << 14) + (lane << 4);
  bB[0] = lds + 65536 + ((wn >> 1) << 14) + ((wn & 1) << 13) + (lane << 4);
  bB[1] = lds + 65536 + (((wn >> 1) + 2) << 14) + ((wn & 1) << 13) + (lane << 4);

  f32x4 acc[8][4];
#pragma unroll
  for (int mi = 0; mi < 8; ++mi)
#pragma unroll
    for (int ni = 0; ni < 4; ++ni) acc[mi][ni] = f32x4{0.f, 0.f, 0.f, 0.f};

  bf16x8 alo[4][2], ahi[4][2], bh0[2][2], bh1[2][2];

#define CL16(AF, BF, MI0, NJ0)                                                 \
  _Pragma("unroll")                                                            \
  for (int kk = 0; kk < 2; ++kk)                                               \
    _Pragma("unroll")                                                          \
    for (int i = 0; i < 4; ++i)                                                \
      _Pragma("unroll")                                                        \
      for (int j = 0; j < 2; ++j)                                              \
        acc[(MI0) + i][(NJ0) + j] = __builtin_amdgcn_mfma_f32_16x16x32_bf16(   \
            AF[i][kk], BF[j][kk], acc[(MI0) + i][(NJ0) + j], 0, 0, 0);

#define RD_ALO(ab) _Pragma("unroll") for (int i = 0; i < 4; ++i) {             \
    alo[i][0] = *(const bf16x8*)((ab) + (i * 2) * 1024);                       \
    alo[i][1] = *(const bf16x8*)((ab) + (i * 2 + 1) * 1024); }
#define RD_AHI(ab) _Pragma("unroll") for (int i = 0; i < 4; ++i) {             \
    ahi[i][0] = *(const bf16x8*)((ab) + ((i + 4) * 2) * 1024);                 \
    ahi[i][1] = *(const bf16x8*)((ab) + ((i + 4) * 2 + 1) * 1024); }
#define RD_B0(bb) _Pragma("unroll") for (int j = 0; j < 2; ++j) {              \
    bh0[j][0] = *(const bf16x8*)((bb) + (j * 2) * 1024);                       \
    bh0[j][1] = *(const bf16x8*)((bb) + (j * 2 + 1) * 1024); }
#define RD_B1(bb) _Pragma("unroll") for (int j = 0; j < 2; ++j) {              \
    bh1[j][0] = *(const bf16x8*)((bb) + ((j + 2) * 2) * 1024);                 \
    bh1[j][1] = *(const bf16x8*)((bb) + ((j + 2) * 2 + 1) * 1024); }

#define WLG0  asm volatile("s_waitcnt lgkmcnt(0)" ::: "memory");               \
              __builtin_amdgcn_sched_barrier(0)
#define BAR   __builtin_amdgcn_s_barrier()
#define PRIO1 __builtin_amdgcn_s_setprio(1)
#define PRIO0 __builtin_amdgcn_s_setprio(0)

  // ---- prologue: tile0 fully + B(1) = 12 GLL; vmcnt(4) = tile0 landed ----
  STGA_H(0, 0); STGA_H(0, 1); STGB_H(0, 0); STGB_H(0, 1);
  STGB_H(1, 0); STGB_H(1, 1);
  asm volatile("s_waitcnt vmcnt(4)" ::: "memory");
  BAR;

  for (int it = 0; it < 8; ++it) {
    const int t0 = it << 1;
    const int last = (it == 7);
    const char* a0 = aB[0];
    const char* b0 = bB[0];
    const char* a1 = aB[1];
    const char* b1 = bB[1];

    // ======== tile t0 (even, slots 0/1) ========
    // P0: Q(m0,n0): 12 reads; stage A(t0+1)h0
    RD_ALO(a0); RD_B0(b0);
    STGA_H(t0 + 1, 0);
    BAR; WLG0;
    PRIO1; CL16(alo, bh0, 0, 0); PRIO0;
    BAR;
    // P1: Q(m0,n1): 4 reads; stage A(t0+1)h1
    RD_B1(b0);
    STGA_H(t0 + 1, 1);
    BAR; WLG0;
    PRIO1; CL16(alo, bh1, 0, 2); PRIO0;
    BAR;                                   // B slots of t0 released
    // P2: Q(m1,n1): 8 reads; stage B(t0+2)h0
    RD_AHI(a0);
    if (!last) STGB_H(t0 + 2, 0);
    BAR; WLG0;
    PRIO1; CL16(ahi, bh1, 4, 2); PRIO0;
    BAR;                                   // A slots of t0 released
    // P3: Q(m1,n0): 0 reads; stage B(t0+2)h1; vmcnt retires tile t0+1
    if (!last) STGB_H(t0 + 2, 1);
    BAR;
    PRIO1; CL16(ahi, bh0, 4, 0); PRIO0;
    if (last) asm volatile("s_waitcnt vmcnt(0)" ::: "memory");
    else      asm volatile("s_waitcnt vmcnt(4)" ::: "memory");
    BAR;

    // ======== tile t0+1 (odd, slots 2/3) ========
    // P4: Q(m0,n0); stage A(t0+2)h0
    RD_ALO(a1); RD_B0(b1);
    if (!last) STGA_H(t0 + 2, 0);
    BAR; WLG0;
    PRIO1; CL16(alo, bh0, 0, 0); PRIO0;
    BAR;
    // P5: Q(m0,n1); stage A(t0+2)h1
    RD_B1(b1);
    if (!last) STGA_H(t0 + 2, 1);
    BAR; WLG0;
    PRIO1; CL16(alo, bh1, 0, 2); PRIO0;
    BAR;
    // P6: Q(m1,n1); stage B(t0+3)h0
    RD_AHI(a1);
    if (!last) STGB_H(t0 + 3, 0);
    BAR; WLG0;
    PRIO1; CL16(ahi, bh1, 4, 2); PRIO0;
    BAR;
    // P7: Q(m1,n0); stage B(t0+3)h1; vmcnt retires tile t0+2
    if (!last) STGB_H(t0 + 3, 1);
    BAR;
    PRIO1; CL16(ahi, bh0, 4, 0); PRIO0;
    if (!last) asm volatile("s_waitcnt vmcnt(4)" ::: "memory");
    BAR;
  }

  // epilogue: out[n*4096 + m]; 4 acc regs = consecutive m -> float4 store
  const int mbase = (mp << 8) + (wm << 7) + ((lane >> 4) << 2);
  const int nbase = (np << 8) + (wn << 6) + (lane & 15);
#pragma unroll
  for (int mi = 0; mi < 8; ++mi)
#pragma unroll
    for (int ni = 0; ni < 4; ++ni)
      *(f32x4*)(out + (size_t)(nbase + ni * 16) * 4096 + mbase + mi * 16) =
          acc[mi][ni];
#undef STGA_H
#undef STGB_H
#undef CL16
#undef RD_ALO
#undef RD_AHI
#undef RD_B0
#undef RD_B1
#undef WLG0
#undef BAR
#undef PRIO1
#undef PRIO0
}

// ---------- launcher ----------
// setup_inputs order: 0:x 1:qweight_V 2:qzeros_V 3:scales_V 4:g_idx_V
//                     5:qweight_U 6:qzeros_U 7:scales_U 8:g_idx_U 9:S
extern "C" void kernel_launch(void* const* d_in, const int* in_sizes, int n_in,
                              void* d_out, int out_size, void* d_ws, size_t ws_size,
                              hipStream_t stream) {
  const int*   qw_V = (const int*)d_in[1];
  const int*   qz_V = (const int*)d_in[2];
  const float* sc_V = (const float*)d_in[3];
  const int*   qw_U = (const int*)d_in[5];
  const int*   qz_U = (const int*)d_in[6];
  const float* sc_U = (const float*)d_in[7];
  const float* S    = (const float*)d_in[9];

  short* A = (short*)d_ws;                  // 8 MB fragment-major P
  short* B = (short*)d_ws + 4096 * 1024;    // 8 MB fragment-major Qt
  float* out = (float*)d_out;

  dequant_fused<<<4096, 256, 0, stream>>>(qw_V, qz_V, sc_V, S, A,
                                          qw_U, qz_U, sc_U, B);
  gemm256<<<256, 512, 0, stream>>>(A, B, out);
}

// Round 11
// 50.742 us; speedup vs baseline: 1.0325x; 1.0325x over previous
//
#include <hip/hip_runtime.h>

// ---------- types ----------
typedef __attribute__((ext_vector_type(8))) short bf16x8;
typedef __attribute__((ext_vector_type(4))) float f32x4;

__device__ __forceinline__ short f2bf(float f) {
  unsigned u = __builtin_bit_cast(unsigned, f);
  u += 0x7fffu + ((u >> 16) & 1u);   // round-to-nearest-even
  return (short)(u >> 16);
}

// ---------- layout ----------
// IN=4096, OUT=4096, RANK=1024, GROUP=128, PACK=8
// GEMM: out[n*4096+m] = sum_r W_V(m,r)*S(r) * W_U(r,n)
// Tiles: 128x256, BK=32. Fragment-major storage, each 1 KB block = one
// 16x16x32 MFMA fragment in lane order (lane*16B):
//   A elem addr = ((mp*32+kt)*8  + i)*512 + lane*8 + e   (i = 16-row frag 0..7)
//     m = mp*128 + i*16 + (lane&15); r = kt*32 + (lane>>4)*8 + e
//   B elem addr = ((np*32+kt)*16 + j)*512 + lane*8 + e   (j = 16-col frag 0..15)
//     n = np*256 + j*16 + (lane&15); r = kt*32 + (lane>>4)*8 + e

// ---------- stage 1: fused dequant (V -> A, U -> B) ----------
__global__ __launch_bounds__(256) void dequant_fused(
    const int* __restrict__ qw_V, const int* __restrict__ qz_V,
    const float* __restrict__ sc_V, const float* __restrict__ S,
    short* __restrict__ A,
    const int* __restrict__ qw_U, const int* __restrict__ qz_U,
    const float* __restrict__ sc_U, short* __restrict__ B) {
  const int bid = blockIdx.x;
  if (bid < 2048) {
    const int t    = bid * 256 + threadIdx.x;      // 0..524287
    const int tile = t >> 9;                       // mp*32 + kt
    const int blk  = (t >> 6) & 7;                 // i
    const int lane = t & 63;
    const int m  = (tile >> 5) * 128 + blk * 16 + (lane & 15);
    const int r0 = (tile & 31) * 32 + ((lane >> 4) << 3);
    const int g  = m >> 7;
    const int sh = (m & 7) << 2;
    const int zw = qz_V[(g << 7) + (r0 >> 3)];
    const int*   wq  = qw_V + (m >> 3) * 1024 + r0;
    const float* scp = sc_V + (g << 10) + r0;
    const float* sp  = S + r0;
    bf16x8 res;
#pragma unroll
    for (int e = 0; e < 8; ++e) {
      int q = (wq[e] >> sh) & 15;
      int z = ((zw >> (e << 2)) & 15) + 1;
      res[e] = f2bf((float)(q - z) * scp[e] * sp[e]);
    }
    *(bf16x8*)(A + ((size_t)t << 3)) = res;        // coalesced
  } else {
    const int t    = (bid - 2048) * 256 + threadIdx.x;
    const int tile = t >> 10;                      // np*32 + kt
    const int blk  = (t >> 6) & 15;                // j
    const int lane = t & 63;
    const int n  = (tile >> 5) * 256 + blk * 16 + (lane & 15);
    const int r0 = (tile & 31) * 32 + ((lane >> 4) << 3);
    const int w  = qw_U[(r0 >> 3) * 4096 + n];
    const int g  = r0 >> 7;
    const int zw = qz_U[(g << 9) + (n >> 3)];
    const int z  = ((zw >> ((n & 7) << 2)) & 15) + 1;
    const float s = sc_U[(g << 12) + n];
    bf16x8 res;
#pragma unroll
    for (int e = 0; e < 8; ++e) {
      int q = (w >> (e << 2)) & 15;
      res[e] = f2bf((float)(q - z) * s);
    }
    *(bf16x8*)(B + ((size_t)t << 3)) = res;
  }
}

// ---------- stage 2: 128x256, BK=32, 8 waves, 2 blocks/CU ----------
// LDS: buf b at b*24576: A tile (8 KB) at +0, B tile (16 KB) at +8192.
// 48 KB total -> 2 blocks/CU co-resident (512 blocks / 256 CU): cross-block
// TLP hides barriers, vmcnt waits, prologue fill, and the fp32 epilogue tail.
// Per K-step: 3 GLL staging (A:1, B:2), 8 ds_read_b128, 16 MFMA.
// vmcnt ledger: prologue stages t0,t1 (6 GLL) -> vmcnt(3) = t0 landed.
// Steady iter kt: reads; lgkm(0); BAR (all reads of buf done); stage kt+2
// (same buf, now safe); 16 MFMA; vmcnt(3) retires tile kt+1; BAR (publish).
// kt==30: no stage, vmcnt(0). kt==31: no stage, no wait.
#define GLL(g, l)                                                              \
  __builtin_amdgcn_global_load_lds(                                            \
      (const __attribute__((address_space(1))) void*)(g),                      \
      (__attribute__((address_space(3))) void*)(l), 16, 0, 0)

__global__ __launch_bounds__(512, 4) void gemm128x256(
    const short* __restrict__ A, const short* __restrict__ B,
    float* __restrict__ out) {
  __shared__ __align__(16) char lds[49152];
  const int tid  = threadIdx.x;          // 0..511
  const int lane = tid & 63;
  const int wid  = tid >> 6;             // 0..7
  const int wm   = wid >> 2;             // 0..1  (64-row half of 128)
  const int wn   = wid & 3;              // 0..3  (64-col quarter of 256)
  const int bid = ((blockIdx.x & 7) << 6) | (blockIdx.x >> 3);  // T1 bijective, 512=8*64
  const int mp = bid >> 4;               // 0..31
  const int np = bid & 15;               // 0..15

  // staging sources (per-lane); LDS dests are wave-uniform (wid slot)
  const short* gA = A + (size_t)mp * 32768 + tid * 8;   // mp*32 tiles * 4096 elems/8KB... (mp*32+kt)*4096 = mp*131072? no:
  // A tile stride = 4096 elems (8 KB); panel mp covers tiles mp*32..mp*32+31
  // base for kt: A + (mp*32+kt)*4096 + tid*8  -> precompute mp part:
  const short* gAp = A + (size_t)(mp * 32) * 4096 + tid * 8;
  const short* gBp = B + (size_t)(np * 32) * 8192 + tid * 8;
  char* const ldsA = lds + (wid << 10);          // + buf
  char* const ldsB = lds + 8192 + (wid << 10);   // + buf

#define STAGE(kt) do {                                                         \
    const int bo_ = ((kt) & 1) * 24576;                                        \
    GLL(gAp + (size_t)(kt) * 4096, ldsA + bo_);                                \
    GLL(gBp + (size_t)(kt) * 8192, ldsB + bo_);                                \
    GLL(gBp + (size_t)(kt) * 8192 + 4096, ldsB + bo_ + 8192);                  \
  } while (0)

  // fragment read bases
  const char* Ard = lds + (lane << 4);           // + buf + (wm*4+i)*1024
  const char* Brd = lds + 8192 + (lane << 4);    // + buf + (wn*4+j)*1024

  f32x4 acc[4][4];
#pragma unroll
  for (int i = 0; i < 4; ++i)
#pragma unroll
    for (int j = 0; j < 4; ++j) acc[i][j] = f32x4{0.f, 0.f, 0.f, 0.f};

  // ---- prologue ----
  STAGE(0);
  STAGE(1);
  asm volatile("s_waitcnt vmcnt(3)" ::: "memory");
  __builtin_amdgcn_s_barrier();

  for (int kt = 0; kt < 32; ++kt) {
    const int bo = (kt & 1) * 24576;
    bf16x8 a[4], b[4];
#pragma unroll
    for (int i = 0; i < 4; ++i)
      a[i] = *(const bf16x8*)(Ard + bo + ((wm << 2) + i) * 1024);
#pragma unroll
    for (int j = 0; j < 4; ++j)
      b[j] = *(const bf16x8*)(Brd + bo + ((wn << 2) + j) * 1024);
    asm volatile("s_waitcnt lgkmcnt(0)" ::: "memory");
    __builtin_amdgcn_sched_barrier(0);
    __builtin_amdgcn_s_barrier();        // all waves' reads of this buf done
    if (kt < 30) STAGE(kt + 2);          // overwrite now-safe buf
    __builtin_amdgcn_s_setprio(1);
#pragma unroll
    for (int i = 0; i < 4; ++i)
#pragma unroll
      for (int j = 0; j < 4; ++j)
        acc[i][j] = __builtin_amdgcn_mfma_f32_16x16x32_bf16(
            a[i], b[j], acc[i][j], 0, 0, 0);
    __builtin_amdgcn_s_setprio(0);
    if (kt < 30)       asm volatile("s_waitcnt vmcnt(3)" ::: "memory");
    else if (kt == 30) asm volatile("s_waitcnt vmcnt(0)" ::: "memory");
    if (kt < 31) __builtin_amdgcn_s_barrier();   // publish tile kt+1
  }

  // epilogue: out[n*4096 + m]; 4 acc regs = consecutive m -> float4 store
  const int mbase = (mp << 7) + (wm << 6) + ((lane >> 4) << 2);
  const int nbase = (np << 8) + (wn << 6) + (lane & 15);
#pragma unroll
  for (int mi = 0; mi < 4; ++mi)
#pragma unroll
    for (int ni = 0; ni < 4; ++ni)
      *(f32x4*)(out + (size_t)(nbase + ni * 16) * 4096 + mbase + mi * 16) =
          acc[mi][ni];
#undef STAGE
}

// ---------- launcher ----------
// setup_inputs order: 0:x 1:qweight_V 2:qzeros_V 3:scales_V 4:g_idx_V
//                     5:qweight_U 6:qzeros_U 7:scales_U 8:g_idx_U 9:S
extern "C" void kernel_launch(void* const* d_in, const int* in_sizes, int n_in,
                              void* d_out, int out_size, void* d_ws, size_t ws_size,
                              hipStream_t stream) {
  const int*   qw_V = (const int*)d_in[1];
  const int*   qz_V = (const int*)d_in[2];
  const float* sc_V = (const float*)d_in[3];
  const int*   qw_U = (const int*)d_in[5];
  const int*   qz_U = (const int*)d_in[6];
  const float* sc_U = (const float*)d_in[7];
  const float* S    = (const float*)d_in[9];

  short* A = (short*)d_ws;                  // 8 MB fragment-major (V*S)
  short* B = (short*)d_ws + 4096 * 1024;    // 8 MB fragment-major U^T
  float* out = (float*)d_out;

  dequant_fused<<<4096, 256, 0, stream>>>(qw_V, qz_V, sc_V, S, A,
                                          qw_U, qz_U, sc_U, B);
  gemm128x256<<<512, 512, 0, stream>>>(A, B, out);
}